// Round 1
// baseline (51.591 us; speedup 1.0000x reference)
//
#include <hip/hip_runtime.h>

typedef float f4 __attribute__((ext_vector_type(4)));

struct G9 { f4 q[9]; };

// n must be a compile-time constant after unrolling
#define GQn(g, n) ((g).q[(n) >> 2][(n) & 3])
#define MAT(g, k, i, j) GQn(g, 9*(k) + 3*(i) + (j))

__device__ __forceinline__ G9 load_g9(const float* p) {
  G9 g;
  const f4* p4 = (const f4*)p;
#pragma unroll
  for (int i = 0; i < 9; ++i) g.q[i] = p4[i];
  return g;
}

__device__ __forceinline__ float sigm(float z) {
  return __builtin_amdgcn_rcpf(1.0f + __expf(-z));
}
__device__ __forceinline__ float tanh_(float z) {
  float e = __expf(2.0f * z);
  return 1.0f - 2.0f * __builtin_amdgcn_rcpf(e + 1.0f);
}

__device__ __forceinline__ void lstm_step(
    float x0, float x1, float x2,
    float& h0, float& h1, float& h2,
    float& c0, float& c1, float& c2,
    const float (&wi)[12][3], const float (&wh)[12][3], const float (&bs)[12]) {
  float g[12];
#pragma unroll
  for (int k = 0; k < 12; ++k) {
    g[k] = bs[k] + wi[k][0]*x0 + wi[k][1]*x1 + wi[k][2]*x2
                 + wh[k][0]*h0 + wh[k][1]*h1 + wh[k][2]*h2;
  }
  float i0 = sigm(g[0]),  i1 = sigm(g[1]),  i2 = sigm(g[2]);
  float f0 = sigm(g[3]),  f1 = sigm(g[4]),  f2 = sigm(g[5]);
  float t0 = tanh_(g[6]), t1 = tanh_(g[7]), t2 = tanh_(g[8]);
  float o0 = sigm(g[9]),  o1 = sigm(g[10]), o2 = sigm(g[11]);
  c0 = f0*c0 + i0*t0; c1 = f1*c1 + i1*t1; c2 = f2*c2 + i2*t2;
  h0 = o0*tanh_(c0); h1 = o1*tanh_(c1); h2 = o2*tanh_(c2);
}

__global__ __launch_bounds__(64, 1) void gaze_lstm_kernel(
    const float* __restrict__ dir, const float* __restrict__ R,
    const float* __restrict__ Wih, const float* __restrict__ Whh,
    const float* __restrict__ bih, const float* __restrict__ bhh,
    float* __restrict__ out, int B) {
  const int b = blockIdx.x * 64 + threadIdx.x;
  if (b >= B) return;

  // wave-uniform weights -> scalar loads
  float wi[12][3], wh[12][3], bs[12];
#pragma unroll
  for (int k = 0; k < 12; ++k) {
#pragma unroll
    for (int j = 0; j < 3; ++j) { wi[k][j] = Wih[k*3+j]; wh[k][j] = Whh[k*3+j]; }
    bs[k] = bih[k] + bhh[k];
  }

  const float* Rb = R + (size_t)b * 1152;   // 128 frames * 9
  float* ob = out + (size_t)b * 384;        // 128 rows * 3

  const float d0 = dir[3*b+0], d1 = dir[3*b+1], d2 = dir[3*b+2];
  float vb0 = d0, vb1 = d1, vb2 = d2;   // backward chain state
  float vf0 = d0, vf1 = d1, vf2 = d2;   // forward chain state
  float h0 = 0.f, h1 = 0.f, h2 = 0.f, c0 = 0.f, c1 = 0.f, c2 = 0.f;
  float cr0 = 0.f, cr1 = 0.f, cr2 = 0.f;  // forward row carry

  // groups of 4 frames: group g covers frames 4g..4g+3 = 9 aligned float4
  G9 Bc = load_g9(Rb + 15*36);  // frames 63..60
  G9 Fc = load_g9(Rb + 16*36);  // frames 64..67

#pragma unroll 2
  for (int it = 0; it < 16; ++it) {
    G9 Bn, Fn;
    const bool pre = (it < 15);
    if (pre) {
      Bn = load_g9(Rb + (size_t)(14 - it) * 36);
      Fn = load_g9(Rb + (size_t)(17 + it) * 36);
    }

    // ---- backward chain + LSTM: frames 4*(15-it)+3 down to 4*(15-it),
    //      producing dirs rows 4it..4it+3 (LSTM steps in that same order)
    float rw[12];
#pragma unroll
    for (int kk = 0; kk < 4; ++kk) {
      const int k = 3 - kk;  // frame within group, descending
      float n0 = MAT(Bc,k,0,0)*vb0 + MAT(Bc,k,1,0)*vb1 + MAT(Bc,k,2,0)*vb2;
      float n1 = MAT(Bc,k,0,1)*vb0 + MAT(Bc,k,1,1)*vb1 + MAT(Bc,k,2,1)*vb2;
      float n2 = MAT(Bc,k,0,2)*vb0 + MAT(Bc,k,1,2)*vb1 + MAT(Bc,k,2,2)*vb2;
      vb0 = n0; vb1 = n1; vb2 = n2;
      rw[3*kk+0] = n0; rw[3*kk+1] = n1; rw[3*kk+2] = n2;
      lstm_step(n0, n1, n2, h0, h1, h2, c0, c1, c2, wi, wh, bs);
    }
    {
      f4 s0 = {rw[0], rw[1], rw[2],  rw[3]};
      f4 s1 = {rw[4], rw[5], rw[6],  rw[7]};
      f4 s2 = {rw[8], rw[9], rw[10], rw[11]};
      f4* op = (f4*)(ob + it*12);
      op[0] = s0; op[1] = s1; op[2] = s2;
    }

    // ---- forward chain: frames 64+4it .. 67+4it, emitting rows frame+1
    float e[4][3];
#pragma unroll
    for (int k = 0; k < 4; ++k) {
      if (!(k == 3 && it == 15)) {  // frame 127 unused
        float n0 = MAT(Fc,k,0,0)*vf0 + MAT(Fc,k,0,1)*vf1 + MAT(Fc,k,0,2)*vf2;
        float n1 = MAT(Fc,k,1,0)*vf0 + MAT(Fc,k,1,1)*vf1 + MAT(Fc,k,1,2)*vf2;
        float n2 = MAT(Fc,k,2,0)*vf0 + MAT(Fc,k,2,1)*vf1 + MAT(Fc,k,2,2)*vf2;
        vf0 = n0; vf1 = n1; vf2 = n2;
      }
      e[k][0] = vf0; e[k][1] = vf1; e[k][2] = vf2;
    }
    if (it == 0) {
      // rows 65..67 (unaligned head)
      ob[195] = e[0][0]; ob[196] = e[0][1]; ob[197] = e[0][2];
      ob[198] = e[1][0]; ob[199] = e[1][1]; ob[200] = e[1][2];
      ob[201] = e[2][0]; ob[202] = e[2][1]; ob[203] = e[2][2];
    } else {
      // aligned flush of rows 64+4it .. 67+4it = [carry, e0, e1, e2]
      f4 t0 = {cr0, cr1, cr2, e[0][0]};
      f4 t1 = {e[0][1], e[0][2], e[1][0], e[1][1]};
      f4 t2 = {e[1][2], e[2][0], e[2][1], e[2][2]};
      f4* fp = (f4*)(ob + (64 + 4*it)*3);
      fp[0] = t0; fp[1] = t1; fp[2] = t2;
    }
    cr0 = e[3][0]; cr1 = e[3][1]; cr2 = e[3][2];

    if (pre) { Bc = Bn; Fc = Fn; }
  }

  // final LSTM step t=64 with x = dir; h replaces row 64
  lstm_step(d0, d1, d2, h0, h1, h2, c0, c1, c2, wi, wh, bs);
  ob[192] = h0; ob[193] = h1; ob[194] = h2;
}

extern "C" void kernel_launch(void* const* d_in, const int* in_sizes, int n_in,
                              void* d_out, int out_size, void* d_ws, size_t ws_size,
                              hipStream_t stream) {
  const float* dir = (const float*)d_in[0];
  const float* R   = (const float*)d_in[1];
  const float* Wih = (const float*)d_in[2];
  const float* Whh = (const float*)d_in[3];
  const float* bih = (const float*)d_in[4];
  const float* bhh = (const float*)d_in[5];
  float* out = (float*)d_out;

  const int B = in_sizes[0] / 3;  // 16384
  const int block = 64;
  const int grid = (B + block - 1) / block;  // 256 blocks -> 1 per CU
  hipLaunchKernelGGL(gaze_lstm_kernel, dim3(grid), dim3(block), 0, stream,
                     dir, R, Wih, Whh, bih, bhh, out, B);
}